// Round 8
// baseline (272.215 us; speedup 1.0000x reference)
//
#include <hip/hip_runtime.h>
#include <hip/hip_bf16.h>

// Problem constants
#define BB 8
#define TT 2048
#define EE 1024
#define HH 64

typedef __attribute__((ext_vector_type(8))) short short8;
typedef __attribute__((ext_vector_type(4))) float f32x4;

__device__ inline f32x4 mfma_16x16x32(short8 a, short8 b, f32x4 c) {
  return __builtin_amdgcn_mfma_f32_16x16x32_bf16(a, b, c, 0, 0, 0);
}

// async global->LDS, 16B per lane, LDS dest = wave-uniform base + lane*16
__device__ inline void gload_lds16(const __hip_bfloat16* g, __hip_bfloat16* l) {
  __builtin_amdgcn_global_load_lds((const __attribute__((address_space(1))) void*)g,
                                   (__attribute__((address_space(3))) void*)l,
                                   16, 0, 0);
}

__device__ inline short f2bf(float f) {
  __hip_bfloat16 h = __float2bfloat16(f);
  return *reinterpret_cast<short*>(&h);
}
__device__ inline float bf2f(short s) {
  __hip_bfloat16 h = *reinterpret_cast<__hip_bfloat16*>(&s);
  return __bfloat162float(h);
}

// wait lgkmcnt(0) only; leave vmcnt/expcnt unconstrained
#define WAIT_LGKM0() __builtin_amdgcn_s_waitcnt(0xC07F)

// ---------------------------------------------------------------------------
// Kernel 0: split-precision transposed weights (unchanged).
// ---------------------------------------------------------------------------
__global__ void prep_w(const float* __restrict__ Wq, const float* __restrict__ Wk,
                       const float* __restrict__ Wv,
                       __hip_bfloat16* __restrict__ Wthi,
                       __hip_bfloat16* __restrict__ Wtlo) {
  const int n = blockIdx.x;          // 0..191
  const int m = n >> 6;
  const int h = n & 63;
  const float* W = (m == 0) ? Wq : (m == 1) ? Wk : Wv;
  const int e0 = threadIdx.x * 4;    // 256 threads * 4 = 1024
#pragma unroll
  for (int j = 0; j < 4; ++j) {
    const float w = W[(e0 + j) * 64 + h];
    const __hip_bfloat16 hi = __float2bfloat16(w);
    Wthi[n * 1024 + e0 + j] = hi;
    Wtlo[n * 1024 + e0 + j] = __float2bfloat16(w - __bfloat162float(hi));
  }
}

// ---------------------------------------------------------------------------
// Kernel A v2: split-bf16 GEMM, occupancy-first.
// 512 blocks x 32 rows. Waves: (row-half 0/1) x (col-half 0..95 / 96..191).
// A (x) read DIRECT from global per lane (not shared across waves -> no LDS,
// no A-barriers), hi/lo split in-register. B in LDS only: K-chunk 32,
// double-buffered hi+lo = 41 KB -> 3 blocks/CU. XOR-swizzled gl_lds staging.
// v-columns (n>=128) hi-only as before.
// ---------------------------------------------------------------------------
__global__ __launch_bounds__(256, 3) void qkv_gemm(
    const float* __restrict__ x,
    const __hip_bfloat16* __restrict__ Wthi, const __hip_bfloat16* __restrict__ Wtlo,
    __hip_bfloat16* __restrict__ qhi, __hip_bfloat16* __restrict__ qlo,
    __hip_bfloat16* __restrict__ khi, __hip_bfloat16* __restrict__ klo,
    __hip_bfloat16* __restrict__ vT) {
  __shared__ __hip_bfloat16 Bhi[2][192 * 32];   // 192 n-rows x 32 k, swizzled
  __shared__ __hip_bfloat16 Blo[2][128 * 32];   // q,k n-rows only

  const int tid  = threadIdx.x;
  const int wave = tid >> 6;
  const int lane = tid & 63;
  const int l15 = lane & 15, l4 = lane >> 4;

  const int row0    = blockIdx.x * 32;
  const int rowbase = row0 + (wave & 1) * 16;
  const int colbase = (wave >> 1) * 96;

  // this lane's x source: row rowbase+l15, k window l4*8 (+c*32 per chunk)
  const float* xsrc = x + (rowbase + l15) * 1024 + l4 * 8;

  f32x4 acc[6];
#pragma unroll
  for (int j = 0; j < 6; ++j) acc[j] = f32x4{0.f, 0.f, 0.f, 0.f};

  // B staging: slot = q*64 + lane; row = slot>>2; g = (slot&3)^(row&3)
  auto issue_B = [&](int c, int buf) {
#pragma unroll
    for (int s = 0; s < 3; ++s) {                 // hi: 12 instr / 4 waves
      const int q   = wave * 3 + s;
      const int slot = q * 64 + lane;
      const int row = slot >> 2;
      const int g   = (slot & 3) ^ (row & 3);
      gload_lds16(Wthi + row * 1024 + c * 32 + g * 8, &Bhi[buf][q * 512]);
    }
#pragma unroll
    for (int s = 0; s < 2; ++s) {                 // lo: 8 instr / 4 waves
      const int q   = wave * 2 + s;
      const int slot = q * 64 + lane;
      const int row = slot >> 2;
      const int g   = (slot & 3) ^ (row & 3);
      gload_lds16(Wtlo + row * 1024 + c * 32 + g * 8, &Blo[buf][q * 512]);
    }
  };

  // ---- prologue ----
  f32x4 xc0 = *(const f32x4*)(xsrc);
  f32x4 xc1 = *(const f32x4*)(xsrc + 4);
  issue_B(0, 0);
  __syncthreads();   // drains gl_lds (vmcnt0 before barrier)

  for (int c = 0; c < 32; ++c) {
    const int p = c & 1;
    f32x4 xn0, xn1;
    if (c < 31) {
      xn0 = *(const f32x4*)(xsrc + (c + 1) * 32);
      xn1 = *(const f32x4*)(xsrc + (c + 1) * 32 + 4);
      issue_B(c + 1, p ^ 1);
    }

    // in-register hi/lo split of this lane's 8 x-floats
    short8 ah, al;
    {
      float f[8] = {xc0[0], xc0[1], xc0[2], xc0[3], xc1[0], xc1[1], xc1[2], xc1[3]};
#pragma unroll
      for (int i = 0; i < 8; ++i) {
        const short h = f2bf(f[i]);
        ah[i] = h;
        al[i] = f2bf(f[i] - bf2f(h));
      }
    }

#pragma unroll
    for (int j = 0; j < 6; ++j) {
      const int n0 = colbase + j * 16;     // wave-uniform group base
      const int n  = n0 + l15;
      const int g  = (l4 ^ (n & 3)) * 8;
      short8 bh = *(const short8*)&Bhi[p][n * 32 + g];
      acc[j] = mfma_16x16x32(ah, bh, acc[j]);
      if (n0 < 128) {                      // q,k need lo-correction
        short8 bl = *(const short8*)&Blo[p][n * 32 + g];
        acc[j] = mfma_16x16x32(ah, bl, acc[j]);
        acc[j] = mfma_16x16x32(al, bh, acc[j]);
      }
    }
    xc0 = xn0; xc1 = xn1;
    __syncthreads();
  }

  // ---- epilogue: C-layout; split-store q,k; v hi-only transposed ----
#pragma unroll
  for (int j = 0; j < 6; ++j) {
    const int n  = colbase + j * 16 + l15;
    const int mm = n >> 6;
    const int h  = n & 63;
#pragma unroll
    for (int r = 0; r < 4; ++r) {
      const int trow = rowbase + l4 * 4 + r;
      const float val = acc[j][r];
      const __hip_bfloat16 hi = __float2bfloat16(val);
      if (mm == 0) {
        qhi[trow * 64 + h] = hi;
        qlo[trow * 64 + h] = __float2bfloat16(val - __bfloat162float(hi));
      } else if (mm == 1) {
        khi[trow * 64 + h] = hi;
        klo[trow * 64 + h] = __float2bfloat16(val - __bfloat162float(hi));
      } else {
        const int bb = trow >> 11, tl = trow & 2047;
        vT[(bb * 64 + h) * 2048 + tl] = hi;
      }
    }
  }
}

// ---------------------------------------------------------------------------
// Kernel B v7: barrier-free balanced flash attention.
// Wave unit = (b, 16-row strip s in 0..127, chunk ci of <=4 K-tiles).
// nch(s) = s/16+1 (<=8); padded 8-slot decode, idle waves exit.
// Grid 2048 = 8 batches (bid&7, XCD-local) x 256 ublocks; s big-first.
// No __syncthreads anywhere. nch==1 strips write out directly; others write
// normalized bf16 partials + fp32 (m,l) merged by attn_merge.
// ---------------------------------------------------------------------------
__global__ __launch_bounds__(256, 2) void attn_part(
    const __hip_bfloat16* __restrict__ qhi, const __hip_bfloat16* __restrict__ qlo,
    const __hip_bfloat16* __restrict__ khi, const __hip_bfloat16* __restrict__ klo,
    const __hip_bfloat16* __restrict__ vT,
    float* __restrict__ out,
    __hip_bfloat16* __restrict__ partO, float* __restrict__ partM,
    float* __restrict__ partL) {
  __shared__ __hip_bfloat16 Psm[4][16 * 72];   // per-wave P transpose (9.2 KB)

  const int tid  = threadIdx.x;
  const int wave = tid >> 6;
  const int lane = tid & 63;
  const int l15 = lane & 15, l4 = lane >> 4;

  const int b    = blockIdx.x & 7;                 // XCD-local batch
  const int unit = (blockIdx.x >> 3) * 4 + wave;   // 0..1023
  const int s    = 127 - (unit >> 3);              // big strips first
  const int ci   = unit & 7;
  const int t    = (s >> 2) + 1;                   // causal 64-key tiles
  const int nch  = (s >> 4) + 1;                   // chunks for this strip
  if (ci >= nch) return;                           // idle slot
  const int tb = ci * 4;
  const int te = min(tb + 4, t);
  const int t0 = s * 16;

  // ---- Q A-frags (16 rows), hi+lo ----
  const __hip_bfloat16* qph = qhi + (b * 2048 + t0 + l15) * 64;
  const __hip_bfloat16* qpl = qlo + (b * 2048 + t0 + l15) * 64;
  short8 qh0 = *(const short8*)(qph + l4 * 8);
  short8 qh1 = *(const short8*)(qph + 32 + l4 * 8);
  short8 ql0 = *(const short8*)(qpl + l4 * 8);
  short8 ql1 = *(const short8*)(qpl + 32 + l4 * 8);

  f32x4 acc[4];
#pragma unroll
  for (int j = 0; j < 4; ++j) acc[j] = f32x4{0.f, 0.f, 0.f, 0.f};
  float m_[4] = {-1e30f, -1e30f, -1e30f, -1e30f};
  float l_[4] = {0.f, 0.f, 0.f, 0.f};

  const __hip_bfloat16* kbase_h = khi + (size_t)b * 2048 * 64;
  const __hip_bfloat16* kbase_l = klo + (size_t)b * 2048 * 64;
  const __hip_bfloat16* vbase   = vT + (size_t)b * 64 * 2048;

  for (int kt = tb; kt < te; ++kt) {
    const int k0 = kt << 6;
    const bool diag = (kt == t - 1);
    const int jmax = s & 3;            // on diag tile: j<jmax full, ==jmax partial

    f32x4 s_[4];
#pragma unroll
    for (int j = 0; j < 4; ++j) {
      if (diag && j > jmax) {
        s_[j] = f32x4{-1e30f, -1e30f, -1e30f, -1e30f};
        continue;
      }
      const __hip_bfloat16* kph = kbase_h + (k0 + j * 16 + l15) * 64;
      const __hip_bfloat16* kpl = kbase_l + (k0 + j * 16 + l15) * 64;
      short8 kh0 = *(const short8*)(kph + l4 * 8);
      short8 kh1 = *(const short8*)(kph + 32 + l4 * 8);
      short8 kl0 = *(const short8*)(kpl + l4 * 8);
      short8 kl1 = *(const short8*)(kpl + 32 + l4 * 8);
      f32x4 z = f32x4{0.f, 0.f, 0.f, 0.f};
      z = mfma_16x16x32(qh0, kh0, z);
      z = mfma_16x16x32(qh1, kh1, z);
      z = mfma_16x16x32(qh0, kl0, z);
      z = mfma_16x16x32(qh1, kl1, z);
      z = mfma_16x16x32(ql0, kh0, z);
      z = mfma_16x16x32(ql1, kh1, z);
      s_[j] = z;
    }
    if (diag) {   // partial mask on j == jmax: key_local > row_local
#pragma unroll
      for (int r = 0; r < 4; ++r)
        if (l15 > l4 * 4 + r) s_[jmax][r] = -1e30f;
    }

    // ---- online softmax (4 rows/lane; 16-lane col-group reduction) ----
    float mx[4], rs[4], al[4];
#pragma unroll
    for (int r = 0; r < 4; ++r)
      mx[r] = fmaxf(fmaxf(s_[0][r], s_[1][r]), fmaxf(s_[2][r], s_[3][r]));
    for (int off = 1; off < 16; off <<= 1) {
#pragma unroll
      for (int r = 0; r < 4; ++r) mx[r] = fmaxf(mx[r], __shfl_xor(mx[r], off));
    }
#pragma unroll
    for (int r = 0; r < 4; ++r) {
      const float mn = fmaxf(m_[r], mx[r]);
      al[r] = __expf(m_[r] - mn);
      m_[r] = mn;
      rs[r] = 0.f;
    }
#pragma unroll
    for (int j = 0; j < 4; ++j) {
#pragma unroll
      for (int r = 0; r < 4; ++r) {
        const float pv = __expf(s_[j][r] - m_[r]);
        s_[j][r] = pv;
        rs[r] += pv;
      }
    }
    for (int off = 1; off < 16; off <<= 1) {
#pragma unroll
      for (int r = 0; r < 4; ++r) rs[r] += __shfl_xor(rs[r], off);
    }
#pragma unroll
    for (int r = 0; r < 4; ++r) l_[r] = l_[r] * al[r] + rs[r];
#pragma unroll
    for (int j = 0; j < 4; ++j)
#pragma unroll
      for (int r = 0; r < 4; ++r) acc[j][r] *= al[r];

    // ---- P: C-layout -> per-wave LDS -> A-layout ----
#pragma unroll
    for (int j = 0; j < 4; ++j)
#pragma unroll
      for (int r = 0; r < 4; ++r)
        Psm[wave][(l4 * 4 + r) * 72 + j * 16 + l15] = __float2bfloat16(s_[j][r]);

    // V frags issued before the lgkm-only wait (stay in flight)
    short8 vf0[4], vf1[4];
#pragma unroll
    for (int j = 0; j < 4; ++j) {
      const __hip_bfloat16* vp = vbase + (j * 16 + l15) * 2048 + k0;
      vf0[j] = *(const short8*)(vp + l4 * 8);
      vf1[j] = *(const short8*)(vp + 32 + l4 * 8);
    }
    WAIT_LGKM0();
    short8 pf0 = *(const short8*)&Psm[wave][l15 * 72 + l4 * 8];
    short8 pf1 = *(const short8*)&Psm[wave][l15 * 72 + 32 + l4 * 8];

#pragma unroll
    for (int j = 0; j < 4; ++j) {
      acc[j] = mfma_16x16x32(pf0, vf0[j], acc[j]);
      acc[j] = mfma_16x16x32(pf1, vf1[j], acc[j]);
    }
  }

  // ---- epilogue ----
  if (nch == 1) {        // whole strip done here: write out directly
    float inv[4];
#pragma unroll
    for (int r = 0; r < 4; ++r) inv[r] = 1.f / l_[r];
#pragma unroll
    for (int j = 0; j < 4; ++j)
#pragma unroll
      for (int r = 0; r < 4; ++r)
        out[(b * 2048 + t0 + l4 * 4 + r) * 64 + j * 16 + l15] =
            acc[j][r] * inv[r];
  } else {               // normalized bf16 partial + fp32 (m,l)
    const int pidx = (b * 128 + s) * 8 + ci;
    float inv[4];
#pragma unroll
    for (int r = 0; r < 4; ++r) inv[r] = (l_[r] > 0.f) ? 1.f / l_[r] : 0.f;
#pragma unroll
    for (int j = 0; j < 4; ++j)
#pragma unroll
      for (int r = 0; r < 4; ++r)
        partO[(size_t)pidx * 1024 + (l4 * 4 + r) * 64 + j * 16 + l15] =
            __float2bfloat16(acc[j][r] * inv[r]);
    if (l15 == 0) {
#pragma unroll
      for (int r = 0; r < 4; ++r) {
        partM[pidx * 16 + l4 * 4 + r] = m_[r];
        partL[pidx * 16 + l4 * 4 + r] = l_[r];
      }
    }
  }
}

// ---------------------------------------------------------------------------
// Kernel C: merge 2..8 partials for strips s>=16. Grid 896 = 8 x 112, 64 thr.
// ---------------------------------------------------------------------------
__global__ __launch_bounds__(64) void attn_merge(
    const __hip_bfloat16* __restrict__ partO, const float* __restrict__ partM,
    const float* __restrict__ partL, float* __restrict__ out) {
  const int b = blockIdx.x / 112;
  const int s = 16 + blockIdx.x % 112;
  const int nch = (s >> 4) + 1;        // 2..8
  const int h = threadIdx.x;           // 0..63
  const int pb = (b * 128 + s) * 8;

  for (int row = 0; row < 16; ++row) {
    float M = -1e30f;
    for (int c = 0; c < nch; ++c) M = fmaxf(M, partM[(pb + c) * 16 + row]);
    float L = 0.f, O = 0.f;
    for (int c = 0; c < nch; ++c) {
      const float a = __expf(partM[(pb + c) * 16 + row] - M) *
                      partL[(pb + c) * 16 + row];
      L += a;
      O += a * __bfloat162float(partO[(size_t)(pb + c) * 1024 + row * 64 + h]);
    }
    out[(b * 2048 + s * 16 + row) * 64 + h] = O / L;
  }
}

// ---------------------------------------------------------------------------
extern "C" void kernel_launch(void* const* d_in, const int* in_sizes, int n_in,
                              void* d_out, int out_size, void* d_ws, size_t ws_size,
                              hipStream_t stream) {
  const float* x  = (const float*)d_in[0];
  const float* Wq = (const float*)d_in[1];
  const float* Wk = (const float*)d_in[2];
  const float* Wv = (const float*)d_in[3];
  float* out = (float*)d_out;

  char* ws = (char*)d_ws;
  __hip_bfloat16* Wthi = (__hip_bfloat16*)ws;                   // 384 KB
  __hip_bfloat16* Wtlo = (__hip_bfloat16*)(ws + 393216);        // 384 KB
  __hip_bfloat16* qhi  = (__hip_bfloat16*)(ws + 786432);        // 2 MB each
  __hip_bfloat16* qlo  = (__hip_bfloat16*)(ws + 786432 + 1 * 2097152);
  __hip_bfloat16* khi  = (__hip_bfloat16*)(ws + 786432 + 2 * 2097152);
  __hip_bfloat16* klo  = (__hip_bfloat16*)(ws + 786432 + 3 * 2097152);
  __hip_bfloat16* vT   = (__hip_bfloat16*)(ws + 786432 + 4 * 2097152);
  char* p = ws + 786432 + 5 * 2097152;                          // 11.27 MB
  __hip_bfloat16* partO = (__hip_bfloat16*)p;                   // 16 MB
  float* partM = (float*)(p + 16777216);                        // 512 KB
  float* partL = (float*)(p + 16777216 + 524288);               // 512 KB

  prep_w<<<192, 256, 0, stream>>>(Wq, Wk, Wv, Wthi, Wtlo);
  qkv_gemm<<<512, 256, 0, stream>>>(x, Wthi, Wtlo, qhi, qlo, khi, klo, vT);
  attn_part<<<2048, 256, 0, stream>>>(qhi, qlo, khi, klo, vT, out,
                                      partO, partM, partL);
  attn_merge<<<896, 64, 0, stream>>>(partO, partM, partL, out);
}

// Round 9
// 214.060 us; speedup vs baseline: 1.2717x; 1.2717x over previous
//
#include <hip/hip_runtime.h>
#include <hip/hip_bf16.h>

// Problem constants
#define BB 8
#define TT 2048
#define EE 1024
#define HH 64

typedef __attribute__((ext_vector_type(8))) short short8;
typedef __attribute__((ext_vector_type(4))) float f32x4;

__device__ inline f32x4 mfma_16x16x32(short8 a, short8 b, f32x4 c) {
  return __builtin_amdgcn_mfma_f32_16x16x32_bf16(a, b, c, 0, 0, 0);
}

// async global->LDS, 16B per lane, LDS dest = wave-uniform base + lane*16
__device__ inline void gload_lds16(const __hip_bfloat16* g, __hip_bfloat16* l) {
  __builtin_amdgcn_global_load_lds((const __attribute__((address_space(1))) void*)g,
                                   (__attribute__((address_space(3))) void*)l,
                                   16, 0, 0);
}

__device__ inline short f2bf(float f) {
  __hip_bfloat16 h = __float2bfloat16(f);
  return *reinterpret_cast<short*>(&h);
}
__device__ inline float bf2f(short s) {
  __hip_bfloat16 h = *reinterpret_cast<__hip_bfloat16*>(&s);
  return __bfloat162float(h);
}

// wait lgkmcnt(0) only; leave vmcnt/expcnt unconstrained
#define WAIT_LGKM0() __builtin_amdgcn_s_waitcnt(0xC07F)

// ---------------------------------------------------------------------------
// Kernel 0: split-precision transposed weights (unchanged).
// ---------------------------------------------------------------------------
__global__ void prep_w(const float* __restrict__ Wq, const float* __restrict__ Wk,
                       const float* __restrict__ Wv,
                       __hip_bfloat16* __restrict__ Wthi,
                       __hip_bfloat16* __restrict__ Wtlo) {
  const int n = blockIdx.x;          // 0..191
  const int m = n >> 6;
  const int h = n & 63;
  const float* W = (m == 0) ? Wq : (m == 1) ? Wk : Wv;
  const int e0 = threadIdx.x * 4;    // 256 threads * 4 = 1024
#pragma unroll
  for (int j = 0; j < 4; ++j) {
    const float w = W[(e0 + j) * 64 + h];
    const __hip_bfloat16 hi = __float2bfloat16(w);
    Wthi[n * 1024 + e0 + j] = hi;
    Wtlo[n * 1024 + e0 + j] = __float2bfloat16(w - __bfloat162float(hi));
  }
}

// ---------------------------------------------------------------------------
// Kernel A: split-bf16 fp32-emulated GEMM (R7's known-good version, 42.8us).
// ---------------------------------------------------------------------------
__global__ __launch_bounds__(256) void qkv_gemm(
    const float* __restrict__ x,
    const __hip_bfloat16* __restrict__ Wthi, const __hip_bfloat16* __restrict__ Wtlo,
    __hip_bfloat16* __restrict__ qhi, __hip_bfloat16* __restrict__ qlo,
    __hip_bfloat16* __restrict__ khi, __hip_bfloat16* __restrict__ klo,
    __hip_bfloat16* __restrict__ vT) {
  __shared__ __hip_bfloat16 Ahi[2][64 * 72];
  __shared__ __hip_bfloat16 Alo[2][64 * 72];
  __shared__ __hip_bfloat16 Bhi[2][192 * 64];
  __shared__ __hip_bfloat16 Blo[2][128 * 64];

  const int tid  = threadIdx.x;
  const int wave = tid >> 6;
  const int lane = tid & 63;
  const int row0 = blockIdx.x * 64;

  const int lr = tid >> 2;
  const int le = (tid & 3) * 16;
  const float* xrow = x + (row0 + lr) * 1024 + le;

  f32x4 acc[12];
#pragma unroll
  for (int j = 0; j < 12; ++j) acc[j] = f32x4{0.f, 0.f, 0.f, 0.f};

  const int l15 = lane & 15, l4 = lane >> 4;

  auto issue_B = [&](int c, int buf) {
    const int g = (lane & 7) ^ ((lane >> 3) & 7);
#pragma unroll
    for (int s = 0; s < 6; ++s) {
      const int qq = wave * 6 + s;
      const int n  = qq * 8 + (lane >> 3);
      gload_lds16(Wthi + n * 1024 + c * 64 + g * 8, &Bhi[buf][qq * 512]);
      if (qq < 16)
        gload_lds16(Wtlo + n * 1024 + c * 64 + g * 8, &Blo[buf][qq * 512]);
    }
  };
  auto write_A = [&](int buf, const f32x4* xr) {
    short8 h0, h1, l0, l1;
    const float* xf = (const float*)xr;
#pragma unroll
    for (int j = 0; j < 8; ++j) {
      const float v = xf[j];
      const short h = f2bf(v);
      h0[j] = h;
      l0[j] = f2bf(v - bf2f(h));
    }
#pragma unroll
    for (int j = 0; j < 8; ++j) {
      const float v = xf[8 + j];
      const short h = f2bf(v);
      h1[j] = h;
      l1[j] = f2bf(v - bf2f(h));
    }
    *(short8*)&Ahi[buf][lr * 72 + le]     = h0;
    *(short8*)&Ahi[buf][lr * 72 + le + 8] = h1;
    *(short8*)&Alo[buf][lr * 72 + le]     = l0;
    *(short8*)&Alo[buf][lr * 72 + le + 8] = l1;
  };
  auto compute = [&](int buf) {
    const int tr = wave * 16 + l15;
    short8 ah0 = *(const short8*)&Ahi[buf][tr * 72 + l4 * 8];
    short8 ah1 = *(const short8*)&Ahi[buf][tr * 72 + 32 + l4 * 8];
    short8 al0 = *(const short8*)&Alo[buf][tr * 72 + l4 * 8];
    short8 al1 = *(const short8*)&Alo[buf][tr * 72 + 32 + l4 * 8];
#pragma unroll
    for (int j = 0; j < 12; ++j) {
      const int n  = j * 16 + l15;
      const int o0 = ((l4)     ^ (n & 7)) * 8;
      const int o1 = ((4 + l4) ^ (n & 7)) * 8;
      short8 bh0 = *(const short8*)&Bhi[buf][n * 64 + o0];
      short8 bh1 = *(const short8*)&Bhi[buf][n * 64 + o1];
      acc[j] = mfma_16x16x32(ah0, bh0, acc[j]);
      acc[j] = mfma_16x16x32(ah1, bh1, acc[j]);
      if (j < 8) {
        short8 bl0 = *(const short8*)&Blo[buf][n * 64 + o0];
        short8 bl1 = *(const short8*)&Blo[buf][n * 64 + o1];
        acc[j] = mfma_16x16x32(ah0, bl0, acc[j]);
        acc[j] = mfma_16x16x32(ah1, bl1, acc[j]);
        acc[j] = mfma_16x16x32(al0, bh0, acc[j]);
        acc[j] = mfma_16x16x32(al1, bh1, acc[j]);
      }
    }
  };

  f32x4 xr[4], xn[4];
  {
    const f32x4* p = (const f32x4*)xrow;
    xr[0] = p[0]; xr[1] = p[1]; xr[2] = p[2]; xr[3] = p[3];
  }
  issue_B(0, 0);
  __builtin_amdgcn_s_waitcnt(0);
  write_A(0, xr);
  __syncthreads();

  for (int c = 0; c < 16; ++c) {
    const int p = c & 1;
    if (c < 15) {
      const f32x4* pp = (const f32x4*)(xrow + (c + 1) * 64);
      xn[0] = pp[0]; xn[1] = pp[1]; xn[2] = pp[2]; xn[3] = pp[3];
      issue_B(c + 1, p ^ 1);
    }
    compute(p);
    if (c < 15) {
      __builtin_amdgcn_s_waitcnt(0);
      write_A(p ^ 1, xn);
    }
    __syncthreads();
  }

  const int strip = wave * 16;
#pragma unroll
  for (int j = 0; j < 12; ++j) {
    const int n  = j * 16 + l15;
    const int mm = n >> 6;
    const int h  = n & 63;
#pragma unroll
    for (int r = 0; r < 4; ++r) {
      const int trow = row0 + strip + l4 * 4 + r;
      const float val = acc[j][r];
      const __hip_bfloat16 hi = __float2bfloat16(val);
      const __hip_bfloat16 lo = __float2bfloat16(val - __bfloat162float(hi));
      if (mm == 0) {
        qhi[trow * 64 + h] = hi;
        qlo[trow * 64 + h] = lo;
      } else if (mm == 1) {
        khi[trow * 64 + h] = hi;
        klo[trow * 64 + h] = lo;
      } else {
        const int bb = trow >> 11, tl = trow & 2047;
        vT[(bb * 64 + h) * 2048 + tl] = hi;
      }
    }
  }
}

// ---------------------------------------------------------------------------
// Kernel A2: per-batch maxK2[b] = max_t |k_t|^2 (one block per batch).
// ---------------------------------------------------------------------------
__global__ __launch_bounds__(256) void prep_maxk(
    const __hip_bfloat16* __restrict__ khi, const __hip_bfloat16* __restrict__ klo,
    float* __restrict__ maxK2) {
  __shared__ float red[256];
  const int b = blockIdx.x;
  float mx = 0.f;
  for (int t = threadIdx.x; t < 2048; t += 256) {
    const short8* vh = (const short8*)(khi + (b * 2048 + t) * 64);
    const short8* vl = (const short8*)(klo + (b * 2048 + t) * 64);
    float s = 0.f;
#pragma unroll
    for (int g = 0; g < 8; ++g) {
      short8 a = vh[g], c = vl[g];
#pragma unroll
      for (int i = 0; i < 8; ++i) {
        const float v = bf2f(a[i]) + bf2f(c[i]);
        s += v * v;
      }
    }
    mx = fmaxf(mx, s);
  }
  red[threadIdx.x] = mx;
  __syncthreads();
  for (int o = 128; o > 0; o >>= 1) {
    if (threadIdx.x < o) red[threadIdx.x] = fmaxf(red[threadIdx.x], red[threadIdx.x + o]);
    __syncthreads();
  }
  if (threadIdx.x == 0) maxK2[b] = red[0];
}

// ---------------------------------------------------------------------------
// Kernel A3: per-row softmax bias.
// bias_t = max(q_t.k_t, |q_t|*maxK_b - 85).
// Overflow-safe: s_max <= |q_t|*maxK_b (Cauchy-Schwarz) => s - bias <= 85.
// Underflow-safe: diag score q_t.k_t always in causal window => l >= e^-O(30).
// ---------------------------------------------------------------------------
__global__ __launch_bounds__(256) void prep_bias(
    const __hip_bfloat16* __restrict__ qhi, const __hip_bfloat16* __restrict__ qlo,
    const __hip_bfloat16* __restrict__ khi, const __hip_bfloat16* __restrict__ klo,
    const float* __restrict__ maxK2, float* __restrict__ bias) {
  const int t = blockIdx.x * 256 + threadIdx.x;   // 0..16383
  const int b = t >> 11;
  const short8* qh = (const short8*)(qhi + t * 64);
  const short8* ql = (const short8*)(qlo + t * 64);
  const short8* kh = (const short8*)(khi + t * 64);
  const short8* kl = (const short8*)(klo + t * 64);
  float dot = 0.f, q2 = 0.f;
#pragma unroll
  for (int g = 0; g < 8; ++g) {
    short8 a = qh[g], c = ql[g], d = kh[g], e = kl[g];
#pragma unroll
    for (int i = 0; i < 8; ++i) {
      const float qv = bf2f(a[i]) + bf2f(c[i]);
      const float kv = bf2f(d[i]) + bf2f(e[i]);
      dot += qv * kv;
      q2  += qv * qv;
    }
  }
  bias[t] = fmaxf(dot, sqrtf(q2 * maxK2[b]) - 85.f);
}

// ---------------------------------------------------------------------------
// Kernel B v8: fixed-bias flash attention (no online softmax), K-hi prefetch.
// R7-v6 structure: 32 Q-rows/wave, block of 4 waves = same strip, stride-4
// split-K, fp32 LDS merge, direct out. Per tile: exp(s - bias_row) with the
// precomputed safe bias -> no max reduce, no rescale, per-lane l partials
// (reduced once in epilogue). Partial sums additive across waves.
// Load order per tile: K-lo(cur) -> K-hi(next tile, prefetch) -> V, so vmcnt
// waits on cur never drain the prefetch.
// ---------------------------------------------------------------------------
__global__ __launch_bounds__(256, 2) void attn(
    const __hip_bfloat16* __restrict__ qhi, const __hip_bfloat16* __restrict__ qlo,
    const __hip_bfloat16* __restrict__ khi, const __hip_bfloat16* __restrict__ klo,
    const __hip_bfloat16* __restrict__ vT, const float* __restrict__ bias,
    float* __restrict__ out) {
  __shared__ __hip_bfloat16 Psm[4][2][16 * 72];  // per-wave, per-m P transpose
  __shared__ float Osm[4][32][65];               // per-wave partial O (fp32)
  __shared__ float Lsm[4][32];                   // per-wave partial l

  const int tid  = threadIdx.x;
  const int wave = tid >> 6;
  const int lane = tid & 63;
  const int l15 = lane & 15, l4 = lane >> 4;

  const int b  = blockIdx.x & 7;            // XCD-local batch
  const int ss = 63 - (blockIdx.x >> 3);    // 32-row strip, big-work first
  const int t0 = ss * 32;
  const int ntiles = (ss >> 1) + 1;         // causal 64-key tiles

  // ---- Q A-frags for 2 sub-tiles, hi+lo (32 VGPRs) ----
  short8 qh0[2], qh1[2], ql0[2], ql1[2];
#pragma unroll
  for (int m = 0; m < 2; ++m) {
    const __hip_bfloat16* qph = qhi + (b * 2048 + t0 + m * 16 + l15) * 64;
    const __hip_bfloat16* qpl = qlo + (b * 2048 + t0 + m * 16 + l15) * 64;
    qh0[m] = *(const short8*)(qph + l4 * 8);
    qh1[m] = *(const short8*)(qph + 32 + l4 * 8);
    ql0[m] = *(const short8*)(qpl + l4 * 8);
    ql1[m] = *(const short8*)(qpl + 32 + l4 * 8);
  }

  // per-row bias (4 rows per lane per sub-tile)
  float bs_[2][4];
#pragma unroll
  for (int m = 0; m < 2; ++m)
#pragma unroll
    for (int r = 0; r < 4; ++r)
      bs_[m][r] = bias[b * 2048 + t0 + m * 16 + l4 * 4 + r];

  f32x4 acc[2][4];
#pragma unroll
  for (int m = 0; m < 2; ++m)
#pragma unroll
    for (int j = 0; j < 4; ++j) acc[m][j] = f32x4{0.f, 0.f, 0.f, 0.f};
  float l_[2][4];
#pragma unroll
  for (int m = 0; m < 2; ++m)
#pragma unroll
    for (int r = 0; r < 4; ++r) l_[m][r] = 0.f;

  const __hip_bfloat16* kbase_h = khi + (size_t)b * 2048 * 64;
  const __hip_bfloat16* kbase_l = klo + (size_t)b * 2048 * 64;
  const __hip_bfloat16* vbase   = vT + (size_t)b * 64 * 2048;

  // ---- K-hi prefetch pipeline: current hi frags live across iterations ----
  short8 ch0[4], ch1[4];
  int kt = wave;
  if (kt < ntiles) {
    const int k0 = kt << 6;
#pragma unroll
    for (int j = 0; j < 4; ++j) {
      const __hip_bfloat16* kph = kbase_h + (k0 + j * 16 + l15) * 64;
      ch0[j] = *(const short8*)(kph + l4 * 8);
      ch1[j] = *(const short8*)(kph + 32 + l4 * 8);
    }
  }

  for (; kt < ntiles; kt += 4) {
    const int k0 = kt << 6;
    const bool diag = (kt == ntiles - 1);

    // current-tile K-lo (needed soon; issued FIRST so its wait leaves the
    // prefetch in flight)
    short8 cl0[4], cl1[4];
#pragma unroll
    for (int j = 0; j < 4; ++j) {
      const __hip_bfloat16* kpl = kbase_l + (k0 + j * 16 + l15) * 64;
      cl0[j] = *(const short8*)(kpl + l4 * 8);
      cl1[j] = *(const short8*)(kpl + 32 + l4 * 8);
    }
    // prefetch next tile's K-hi
    short8 nh0[4], nh1[4];
    {
      const int ktn = (kt + 4 < ntiles) ? kt + 4 : kt;
      const int k0n = ktn << 6;
#pragma unroll
      for (int j = 0; j < 4; ++j) {
        const __hip_bfloat16* kph = kbase_h + (k0n + j * 16 + l15) * 64;
        nh0[j] = *(const short8*)(kph + l4 * 8);
        nh1[j] = *(const short8*)(kph + 32 + l4 * 8);
      }
    }
    // V frags issued early: hidden behind exp + P-LDS round-trip
    short8 vf0[4], vf1[4];
#pragma unroll
    for (int j = 0; j < 4; ++j) {
      const __hip_bfloat16* vp = vbase + (j * 16 + l15) * 2048 + k0;
      vf0[j] = *(const short8*)(vp + l4 * 8);
      vf1[j] = *(const short8*)(vp + 32 + l4 * 8);
    }

#pragma unroll
    for (int m = 0; m < 2; ++m) {
      const int rowbase = t0 + m * 16;
      f32x4 s_[4];
#pragma unroll
      for (int j = 0; j < 4; ++j) {
        if (diag && (k0 + j * 16) > (rowbase + 15)) {  // fully masked group
          s_[j] = f32x4{-1e30f, -1e30f, -1e30f, -1e30f};
          continue;
        }
        f32x4 z = f32x4{0.f, 0.f, 0.f, 0.f};
        z = mfma_16x16x32(qh0[m], ch0[j], z);   // hi*hi first (prefetched)
        z = mfma_16x16x32(qh1[m], ch1[j], z);
        z = mfma_16x16x32(ql0[m], ch0[j], z);
        z = mfma_16x16x32(ql1[m], ch1[j], z);
        z = mfma_16x16x32(qh0[m], cl0[j], z);   // lo last: max load slack
        z = mfma_16x16x32(qh1[m], cl1[j], z);
        s_[j] = z;
      }
      if (diag) {   // partial mask where key > row
#pragma unroll
        for (int j = 0; j < 4; ++j) {
          const int key = k0 + j * 16 + l15;
#pragma unroll
          for (int r = 0; r < 4; ++r) {
            const int row = rowbase + l4 * 4 + r;
            if (key > row) s_[j][r] = -1e30f;
          }
        }
      }

      // fixed-bias exp: no reduce, no rescale; per-lane l partials
#pragma unroll
      for (int j = 0; j < 4; ++j) {
#pragma unroll
        for (int r = 0; r < 4; ++r) {
          const float pv = __expf(s_[j][r] - bs_[m][r]);
          s_[j][r] = pv;
          l_[m][r] += pv;
        }
      }

      // P (C-layout) -> per-wave per-m LDS buffer
#pragma unroll
      for (int j = 0; j < 4; ++j)
#pragma unroll
        for (int r = 0; r < 4; ++r)
          Psm[wave][m][(l4 * 4 + r) * 72 + j * 16 + l15] =
              __float2bfloat16(s_[j][r]);
    }

    WAIT_LGKM0();   // P LDS writes visible to same wave; vmcnt untouched

    // ---- O += P V ----
#pragma unroll
    for (int m = 0; m < 2; ++m) {
      short8 pf0 = *(const short8*)&Psm[wave][m][l15 * 72 + l4 * 8];
      short8 pf1 = *(const short8*)&Psm[wave][m][l15 * 72 + 32 + l4 * 8];
#pragma unroll
      for (int j = 0; j < 4; ++j) {
        acc[m][j] = mfma_16x16x32(pf0, vf0[j], acc[m][j]);
        acc[m][j] = mfma_16x16x32(pf1, vf1[j], acc[m][j]);
      }
    }

    // rotate prefetched K-hi into current
#pragma unroll
    for (int j = 0; j < 4; ++j) { ch0[j] = nh0[j]; ch1[j] = nh1[j]; }
  }

  // ---- epilogue: reduce l across the 16-lane col group (once per wave) ----
#pragma unroll
  for (int m = 0; m < 2; ++m)
    for (int off = 1; off < 16; off <<= 1) {
#pragma unroll
      for (int r = 0; r < 4; ++r) l_[m][r] += __shfl_xor(l_[m][r], off);
    }

  // per-wave partials into LDS (fp32; same bias per row -> additive)
#pragma unroll
  for (int m = 0; m < 2; ++m) {
#pragma unroll
    for (int j = 0; j < 4; ++j)
#pragma unroll
      for (int r = 0; r < 4; ++r)
        Osm[wave][m * 16 + l4 * 4 + r][j * 16 + l15] = acc[m][j][r];
    if (l15 == 0) {
#pragma unroll
      for (int r = 0; r < 4; ++r)
        Lsm[wave][m * 16 + l4 * 4 + r] = l_[m][r];
    }
  }
  __syncthreads();

  // ---- cross-wave merge: plain sums; wave handles rows [wave*8, +8) ----
#pragma unroll
  for (int rr = 0; rr < 8; ++rr) {
    const int row = wave * 8 + rr;
    float L = Lsm[0][row] + Lsm[1][row] + Lsm[2][row] + Lsm[3][row];
    float O = Osm[0][row][lane] + Osm[1][row][lane] +
              Osm[2][row][lane] + Osm[3][row][lane];
    out[(b * 2048 + t0 + row) * 64 + lane] = O / L;
  }
}

// ---------------------------------------------------------------------------
extern "C" void kernel_launch(void* const* d_in, const int* in_sizes, int n_in,
                              void* d_out, int out_size, void* d_ws, size_t ws_size,
                              hipStream_t stream) {
  const float* x  = (const float*)d_in[0];
  const float* Wq = (const float*)d_in[1];
  const float* Wk = (const float*)d_in[2];
  const float* Wv = (const float*)d_in[3];
  float* out = (float*)d_out;

  char* ws = (char*)d_ws;
  __hip_bfloat16* Wthi = (__hip_bfloat16*)ws;                   // 384 KB
  __hip_bfloat16* Wtlo = (__hip_bfloat16*)(ws + 393216);        // 384 KB
  __hip_bfloat16* qhi  = (__hip_bfloat16*)(ws + 786432);        // 2 MB each
  __hip_bfloat16* qlo  = (__hip_bfloat16*)(ws + 786432 + 1 * 2097152);
  __hip_bfloat16* khi  = (__hip_bfloat16*)(ws + 786432 + 2 * 2097152);
  __hip_bfloat16* klo  = (__hip_bfloat16*)(ws + 786432 + 3 * 2097152);
  __hip_bfloat16* vT   = (__hip_bfloat16*)(ws + 786432 + 4 * 2097152);
  char* p = ws + 786432 + 5 * 2097152;
  float* maxK2 = (float*)p;                                     // 32 B
  float* biasb = (float*)(p + 256);                             // 64 KB

  prep_w<<<192, 256, 0, stream>>>(Wq, Wk, Wv, Wthi, Wtlo);
  qkv_gemm<<<256, 256, 0, stream>>>(x, Wthi, Wtlo, qhi, qlo, khi, klo, vT);
  prep_maxk<<<8, 256, 0, stream>>>(khi, klo, maxK2);
  prep_bias<<<64, 256, 0, stream>>>(qhi, qlo, khi, klo, maxK2, biasb);
  attn<<<512, 256, 0, stream>>>(qhi, qlo, khi, klo, vT, biasb, out);
}